// Round 6
// baseline (222.828 us; speedup 1.0000x reference)
//
#include <hip/hip_runtime.h>
#include <hip/hip_bf16.h>
#include <stdint.h>

// Shapes: N=32, CIN=COUT=64, T=256, V=25, K3=3, G=8
// GCN folded to one GEMM: M=1600 (m=w*64+c), K=1600 (k=cin*25+v), N=8192 (n,t)
//   residual (+x) folded into U's diagonal: U[w*64+c][c*25+w] += 1
// k_prepU: U/biasU factors computed in-block from A/W directly + cwetb/cbe.
// k_xt: separate launch AFTER k_prepU so xb's dirty L2 lines drain before
//   k_gemm (R3 lesson: fused prep left ~32MB dirty -> +15MB writeback during
//   k_gemm's window, 54.7->63.3us).
// k_gemm: R0-proven 256m x 128n tiles, 2-barrier loop, 448 blocks, 2 blk/CU
//   (R1/R2 lesson: 8-phase 256^2 is slower here: 25 K-tiles + 224-block grid
//    = 1 blk/CU, no inter-block overlap; generic XCD swizzle broke B-panel
//    L2 affinity, FETCH 35->95MB. Natural bid mapping keeps bid mod 8 =
//    bn mod 8 -> B-panel reuse XCD-local.)
// k_tcn: MFMA im2col with SWAPPED operands (C^T): lane owns oo=o0+l15 and 4
//   consecutive t*25+v positions -> float4 residual load + float4 NT store.
//   (R5 lesson: __builtin_nontemporal_store needs clang ext_vector type,
//    not HIP_vector_type float4.)
//   OOB window rows read from U's pad rows (zeroed by k_prepU every call)

typedef const float* fp;
typedef __attribute__((ext_vector_type(8))) short short8;   // 8 bf16 (4 VGPRs)
typedef __attribute__((ext_vector_type(4))) float floatx4;  // MFMA acc / NT store

__device__ __forceinline__ float us2f(unsigned int u){
  union { unsigned int i; float f; } c; c.i = u << 16; return c.f;
}
__device__ __forceinline__ unsigned short f2us(float f){
  __hip_bfloat16 h = __float2bfloat16(f);
  return *reinterpret_cast<unsigned short*>(&h);
}
__device__ __forceinline__ void gload_lds16(const void* g, void* l){
  __builtin_amdgcn_global_load_lds(
      (const __attribute__((address_space(1))) void*)g,
      (__attribute__((address_space(3))) void*)l, 16, 0, 0);
}

// ---------------- workspace layout (bytes) ----------------
// cbe   fp32 [64]           @ 117504    (256)
// cwetb bf16 [64][9][64]    @ 117760    (73728)
// biasU fp32 [1600]         @ 191488    (6400)
// U     bf16 [1792][1600]   @ 197888    (5734400)  rows 1600+ = zero page
// xb    bf16 [32][256][1600]@ 5932288   (26214400)
// yb    bf16 [32][256][1600]@ 32146688  (26214400)   total ~58.4 MB

// ---------------- prep A: U rows + biasU + cwetb + cbe ----------------
// blocks [0,1792): U row m + biasU[m]  (factors from A,W,b in-block)
// blocks [1792,1937): cwetb (36864) + cbe (64)
__global__ __launch_bounds__(256) void k_prepU(
    fp A, fp W, fp b, fp g0, fp b0, fp g1, fp b1,
    fp cw, fp cb, fp g2, fp b2,
    unsigned short* U, float* biasU, float* cbe, unsigned short* cwetb)
{
  int bid = blockIdx.x, tid = threadIdx.x;
  const float inv_s = rsqrtf(1.0f + 1e-5f);

  if (bid < 1792) {                     // ---- U rows ----
    int m = bid;
    if (m >= 1600) {                    // zero-pad rows (k_tcn zero page)
      for (int k = tid; k < 1600; k += 256) U[(long long)m*1600 + k] = 0;
      return;
    }
    __shared__ float nAL[75];
    __shared__ float WeffL[192];
    __shared__ float cs3[3];
    int c = m & 63, w = m >> 6, g = c & 7;
    if (tid < 75) {                     // raw A column w for (kk,g)
      int kk = tid / 25, vv = tid % 25;
      nAL[tid] = A[((kk*8 + g)*25 + vv)*25 + w];
    }
    if (tid < 192) {                    // W col c scaled by folded BN0 gain
      int kk = tid >> 6, cin = tid & 63;
      WeffL[tid] = W[cin*192 + kk*64 + c] * (g0[kk*64 + c] * inv_s);
    }
    __syncthreads();
    if (tid < 3) {                      // column sums -> denominators
      float s = 0.f;
      for (int vv = 0; vv < 25; vv++) s += nAL[tid*25 + vv];
      cs3[tid] = s + 0.001f;
    }
    __syncthreads();
    if (tid < 75) nAL[tid] = nAL[tid] / cs3[tid/25];
    __syncthreads();
    float s1 = g1[c] * inv_s;
    for (int k = tid; k < 1600; k += 256) {
      int cin = k / 25, vv = k - cin*25;
      float acc = WeffL[cin]       * nAL[vv]
                + WeffL[64 + cin]  * nAL[25 + vv]
                + WeffL[128 + cin] * nAL[50 + vv];
      acc *= s1;
      if (cin == c && vv == w) acc += 1.0f;  // residual folded into diagonal
      U[(long long)m*1600 + k] = f2us(acc);
    }
    if (tid == 0) {
      float acc = 0.f;
      for (int kk = 0; kk < 3; kk++) {
        int d = kk*64 + c;
        float be = b[d] * (g0[d] * inv_s) + b0[d];
        for (int v = 0; v < 25; v++) acc += be * nAL[kk*25 + v];
      }
      biasU[m] = acc * s1 + b1[c];
    }
    return;
  }

  // ---- cwetb + cbe tail ----
  int gid = (bid - 1792)*256 + tid;
  if (gid < 36864) {                    // cwetb[o][j][i] bf16
    int o = gid / 576, r = gid % 576;
    int j = r / 64, i = r % 64;
    cwetb[gid] = f2us(cw[(o*64+i)*9 + j] * (g2[o] * inv_s));
    return;
  }
  gid -= 36864;
  if (gid < 64) {                       // cbe
    cbe[gid] = cb[gid] * (g2[gid] * inv_s) + b2[gid];
  }
}

// ---------------- transpose x -> bf16 [n][t][cin*25+v] (LDS, coalesced) ----
__global__ __launch_bounds__(256) void k_xt(fp x, unsigned short* xb)
{
  int n = blockIdx.x >> 5, tb = blockIdx.x & 31, t0 = tb*8, tid = threadIdx.x;
  __shared__ unsigned short xs[64*8*26];
  for (int e = tid; e < 12800; e += 256) {
    int c = e / 200, r = e - c*200, tt = r / 25, v = r - tt*25;
    xs[(c*8 + tt)*26 + v] = f2us(x[((n*64 + c)*256 + t0 + tt)*25 + v]);
  }
  __syncthreads();
  for (int e4 = tid; e4 < 3200; e4 += 256) {      // ushort4 stores
    int base = e4 * 4;
    int tt = base / 1600, q0 = base - tt*1600;
    int c = q0 / 25, v = q0 - c*25;
    ushort4 pk;
    pk.x = xs[(c*8 + tt)*26 + v]; if (++v == 25){v = 0; c++;}
    pk.y = xs[(c*8 + tt)*26 + v]; if (++v == 25){v = 0; c++;}
    pk.z = xs[(c*8 + tt)*26 + v]; if (++v == 25){v = 0; c++;}
    pk.w = xs[(c*8 + tt)*26 + v];
    *(ushort4*)(xb + (long long)(n*256 + t0 + tt)*1600 + q0) = pk;
  }
}

// ---------------- GCN GEMM: 256m x 128n, private-A wave strips (R0) ------
__global__ __launch_bounds__(256, 2) void k_gemm(
    const unsigned short* U, const unsigned short* xb, const float* biasU,
    unsigned short* yb)
{
  int bm = blockIdx.x >> 6, bn = blockIdx.x & 63;   // 7 x 64
  int n = bn >> 1, t0 = (bn & 1) * 128;
  int tid = threadIdx.x, lane = tid & 63, wid = tid >> 6;
  int l15 = lane & 15, grp = lane >> 4;

  __shared__ __align__(16) unsigned short As[256*64];  // 32 KB
  __shared__ __align__(16) unsigned short Bs[128*64];  // 16 KB

  const unsigned short* gA[8];
  const unsigned short* gB[4];
  unsigned short* lA[8];
  unsigned short* lB[4];
  #pragma unroll
  for (int it = 0; it < 8; it++) {
    int e = it*256 + tid;
    int row = e >> 3, li = e & 7;
    int kcol = (li ^ (row & 7)) * 8;       // XOR swizzle on global source side
    gA[it] = U + (long long)(bm*256 + row)*1600 + kcol;
    lA[it] = As + e*8;
  }
  #pragma unroll
  for (int it = 0; it < 4; it++) {
    int e = it*256 + tid;
    int row = e >> 3, li = e & 7;
    int kcol = (li ^ (row & 7)) * 8;
    gB[it] = xb + (long long)(n*256 + t0 + row)*1600 + kcol;
    lB[it] = Bs + e*8;
  }

  floatx4 acc[4][8];
  #pragma unroll
  for (int i = 0; i < 4; i++)
    #pragma unroll
    for (int j = 0; j < 8; j++) acc[i][j] = (floatx4){0.f,0.f,0.f,0.f};

  for (int kc = 0; kc < 25; kc++) {
    #pragma unroll
    for (int it = 0; it < 8; it++) gload_lds16(gA[it] + kc*64, lA[it]);
    #pragma unroll
    for (int it = 0; it < 4; it++) gload_lds16(gB[it] + kc*64, lB[it]);
    __syncthreads();
    #pragma unroll
    for (int ks = 0; ks < 2; ks++) {
      int colk = ((ks*4 + grp) ^ (l15 & 7)) * 8;   // un-swizzle at read
      short8 af[4], bf[8];
      #pragma unroll
      for (int i = 0; i < 4; i++)
        af[i] = *(const short8*)(As + (wid*64 + i*16 + l15)*64 + colk);
      #pragma unroll
      for (int j = 0; j < 8; j++)
        bf[j] = *(const short8*)(Bs + (j*16 + l15)*64 + colk);
      #pragma unroll
      for (int i = 0; i < 4; i++)
        #pragma unroll
        for (int j = 0; j < 8; j++)
          acc[i][j] = __builtin_amdgcn_mfma_f32_16x16x32_bf16(af[i], bf[j], acc[i][j], 0, 0, 0);
    }
    __syncthreads();
  }

  #pragma unroll
  for (int i = 0; i < 4; i++) {
    int mbase = bm*256 + wid*64 + i*16 + grp*4;
    if (mbase >= 1600) continue;
    float4 bu = *(const float4*)(biasU + mbase);
    #pragma unroll
    for (int j = 0; j < 8; j++) {
      int col = j*16 + l15;
      int t = t0 + col;
      ushort4 pk;
      pk.x = f2us(fmaxf(acc[i][j][0] + bu.x, 0.f));
      pk.y = f2us(fmaxf(acc[i][j][1] + bu.y, 0.f));
      pk.z = f2us(fmaxf(acc[i][j][2] + bu.z, 0.f));
      pk.w = f2us(fmaxf(acc[i][j][3] + bu.w, 0.f));
      *(ushort4*)(yb + (long long)(n*256 + t)*1600 + mbase) = pk;
    }
  }
}

// ---------------- TCN as MFMA (swapped operands): 512 threads ----------
// 8 waves share one 57 KB window; wave pair (p, p+4) owns o-strip p*16 and
// splits the 13 col-tiles even/odd. mfma(b, af) computes C^T: lane owns
// oo = o0 + l15 and 4 consecutive colb = tile*16 + grp*4 + {0..3}. Since
// out/x are contiguous in t*25+v, residual load + store are one float4 each
// (NT store: out is write-once, keep it out of L2). Fragment layouts for
// A/B roles are identical (idx=l&15, chunk=l>>4) so loading is unchanged.
__global__ __launch_bounds__(512) void k_tcn(
    const unsigned short* yb, const unsigned short* cwetb, const float* cbe,
    fp x, const unsigned short* zpg, float* out)
{
  int n = blockIdx.x >> 5, tb = blockIdx.x & 31, t0 = tb*8;
  int tid = threadIdx.x, lane = tid & 63, wid = tid >> 6;
  int l15 = lane & 15, grp = lane >> 4;
  __shared__ __align__(16) unsigned short ys[3584*8];  // 57344 B (425 rows + pad)

  #pragma unroll
  for (int it = 0; it < 7; it++) {
    int e = it*512 + tid;                 // e < 3584, always full exec
    int row = e >> 3, li = e & 7;
    int rt = row / 25, v = row - rt*25;
    int tg = t0 - 4 + rt;
    int sli = li ^ (row & 7);             // fetch swizzled i-group
    bool ok = (row < 425) && (tg >= 0) && (tg < 256);
    const unsigned short* src = ok
      ? yb + ((long long)(n*256 + tg)*1600 + v*64 + sli*8)
      : zpg + li*8;
    gload_lds16(src, ys + e*8);           // linear LDS deposit
  }

  // A-frags: conv weights in registers, o-strip p = wid&3, half h = wid>>2
  int p = wid & 3, h = wid >> 2;
  int o0 = p * 16;
  int o = o0 + l15;
  short8 af[9][2];
  #pragma unroll
  for (int j = 0; j < 9; j++) {
    af[j][0] = *(const short8*)(cwetb + ((o*9 + j)*64 + grp*8));
    af[j][1] = *(const short8*)(cwetb + ((o*9 + j)*64 + 32 + grp*8));
  }
  float cbv = cbe[o];                     // per-lane scalar (oo = o0 + l15)
  __syncthreads();

  for (int tile = h; tile < 13; tile += 2) {
    int colb = tile*16 + l15;
    floatx4 acc = (floatx4){0.f,0.f,0.f,0.f};
    #pragma unroll
    for (int j = 0; j < 9; j++) {
      int row = colb + 25*j;
      int r7 = row & 7;
      const unsigned short* rb = ys + row*64;
      short8 b0 = *(const short8*)(rb + ((grp     ^ r7))*8);
      short8 b1 = *(const short8*)(rb + (((4+grp) ^ r7))*8);
      acc = __builtin_amdgcn_mfma_f32_16x16x32_bf16(b0, af[j][0], acc, 0, 0, 0);
      acc = __builtin_amdgcn_mfma_f32_16x16x32_bf16(b1, af[j][1], acc, 0, 0, 0);
    }
    int colb0 = tile*16 + grp*4;          // 4 consecutive t*25+v positions
    if (colb0 < 200) {
      long long base = (long long)(n*64 + o)*6400 + t0*25 + colb0;
      floatx4 xv = *(const floatx4*)(x + base);
      floatx4 ov;
      ov.x = fmaxf(acc.x + cbv + xv.x, 0.f);
      ov.y = fmaxf(acc.y + cbv + xv.y, 0.f);
      ov.z = fmaxf(acc.z + cbv + xv.z, 0.f);
      ov.w = fmaxf(acc.w + cbv + xv.w, 0.f);
      __builtin_nontemporal_store(ov, (floatx4*)(out + base));
    }
  }
}

extern "C" void kernel_launch(void* const* d_in, const int* in_sizes, int n_in,
                              void* d_out, int out_size, void* d_ws, size_t ws_size,
                              hipStream_t stream)
{
  fp x  = (fp)d_in[0];
  fp A  = (fp)d_in[1];
  fp W  = (fp)d_in[2];
  fp b  = (fp)d_in[3];
  fp g0 = (fp)d_in[4];
  fp b0 = (fp)d_in[5];
  fp g1 = (fp)d_in[6];
  fp b1 = (fp)d_in[7];
  fp cw = (fp)d_in[8];
  fp cb = (fp)d_in[9];
  fp g2 = (fp)d_in[10];
  fp b2 = (fp)d_in[11];
  // d_in[12] = keep_prob == 1 -> DropBlocks identity.

  char* ws = (char*)d_ws;
  float*          cbe   = (float*)(ws + 117504);
  unsigned short* cwetb = (unsigned short*)(ws + 117760);
  float*          biasU = (float*)(ws + 191488);
  unsigned short* U     = (unsigned short*)(ws + 197888);
  unsigned short* xb    = (unsigned short*)(ws + 5932288);
  unsigned short* yb    = (unsigned short*)(ws + 32146688);
  const unsigned short* zpg = U + (long long)1600*1600;  // zeroed pad rows

  k_prepU<<<1937, 256, 0, stream>>>(A, W, b, g0, b0, g1, b1, cw, cb, g2, b2,
                                    U, biasU, cbe, cwetb);
  k_xt<<<1024, 256, 0, stream>>>(x, xb);
  k_gemm<<<448, 256, 0, stream>>>(U, xb, biasU, yb);
  k_tcn<<<1024, 512, 0, stream>>>(yb, cwetb, cbe, x, zpg, (float*)d_out);
}